// Round 9
// baseline (43.071 us; speedup 1.0000x reference)
//
#include <hip/hip_runtime.h>

#define NG 64
#define NT 8192
#define NE 64
#define Z_COEF 0.001f
#define A_COEF 0.001f

#define BLK 256                  // 4 waves
#define NCHUNK 16                // chunk-steps per wave; 4 tokens (1KB) each
#define TPW 64                   // tokens per wave
#define TPB 256                  // tokens per block
#define NBLK (NG * (NT / TPB))   // 2048 (32 blocks per group)

#define LOG2E 1.44269504088896340736f
#define LN2   0.69314718055994530942f
#define BIGIDX 1048576

#define DPP_XOR1  0xB1           // quad_perm(1,0,3,2)  : lane ^ 1
#define DPP_XOR2  0x4E           // quad_perm(2,3,0,1)  : lane ^ 2
#define DPP_HMIRR 0x141          // row_half_mirror     : lane ^ 7 within 8
#define DPP_MIRR  0x140          // row_mirror          : lane ^ 15 within 16

template <int CTRL>
__device__ __forceinline__ float fdpp(float x) {
    return __int_as_float(__builtin_amdgcn_mov_dpp(__float_as_int(x), CTRL, 0xF, 0xF, true));
}
template <int CTRL>
__device__ __forceinline__ int idpp(int x) {
    return __builtin_amdgcn_mov_dpp(x, CTRL, 0xF, 0xF, true);
}

// ws layout (all written every launch, no zeroing needed):
//   float pps [NBLK][NE]   per-block prob sums
//   uint  pcnt[NBLK][NE]   per-block argmax counts
//   float pz  [NBLK]       per-block z partials

__global__ __launch_bounds__(BLK) void router_main(
    const float* __restrict__ logits,
    float* __restrict__ pps,
    unsigned int* __restrict__ pcnt,
    float* __restrict__ pz)
{
    const int tid  = threadIdx.x;
    const int lane = tid & 63;
    const int wv   = tid >> 6;       // wave in block 0..3
    const int c    = lane & 15;      // expert chunk: experts 4c .. 4c+3
    const int cb   = c << 2;

    const int g     = blockIdx.x >> 5;                  // 32 blocks per group
    const int tbase = (blockIdx.x & 31) * TPB + wv * TPW;

    // fully coalesced: chunk-step s, lane l reads bytes [s*1024 + l*16)
    // of the wave's 16KB token span -> token 4s+(l>>4), experts [4*(l&15),+4)
    const float* p0 = logits + ((size_t)g * NT + tbase) * NE + lane * 4;

    __shared__ float        s_ps[NE];
    __shared__ unsigned int s_cnt[NE];
    __shared__ float        s_z;
    if (tid < NE) { s_ps[tid] = 0.f; s_cnt[tid] = 0u; }
    if (tid == 0) s_z = 0.f;
    __syncthreads();

    float accp[4] = {0.f, 0.f, 0.f, 0.f};
    float accz = 0.f;

    // rolling 3-slot buffer, 2-ahead prefetch: minimal live VGPRs (12 for
    // loads, one chunk-chain live at a time) -- target <=64 VGPR so 8
    // waves/SIMD fit (occupancy halves above 64: R4-R8 plateau suspect).
    float4 buf[3];
    buf[0] = *reinterpret_cast<const float4*>(p0);
    buf[1] = *reinterpret_cast<const float4*>(p0 + 256);

#pragma unroll
    for (int s2 = 0; s2 < NCHUNK; ++s2) {
        if (s2 + 2 < NCHUNK)
            buf[(s2 + 2) % 3] = *reinterpret_cast<const float4*>(p0 + (s2 + 2) * 256);

        const float4 cv = buf[s2 % 3];
        const float v0 = cv.x, v1 = cv.y, v2 = cv.z, v3 = cv.w;

        // group max: local max chain + 4 DPP-fusable fmax stages
        float m = fmaxf(fmaxf(v0, v1), fmaxf(v2, v3));
        m = fmaxf(m, fdpp<DPP_XOR1>(m));
        m = fmaxf(m, fdpp<DPP_XOR2>(m));
        m = fmaxf(m, fdpp<DPP_HMIRR>(m));
        m = fmaxf(m, fdpp<DPP_MIRR>(m));

        // exps straight against group max (base-2, single v_exp each)
        const float e0 = exp2f((v0 - m) * LOG2E);
        const float e1 = exp2f((v1 - m) * LOG2E);
        const float e2 = exp2f((v2 - m) * LOG2E);
        const float e3 = exp2f((v3 - m) * LOG2E);
        float s = (e0 + e1) + (e2 + e3);

        // argmax = first index whose value equals the max (exact ref ties)
        int me = BIGIDX;
        if (v3 == m) me = cb + 3;
        if (v2 == m) me = cb + 2;
        if (v1 == m) me = cb + 1;
        if (v0 == m) me = cb + 0;
        me = min(me, idpp<DPP_XOR1>(me));
        me = min(me, idpp<DPP_XOR2>(me));
        me = min(me, idpp<DPP_HMIRR>(me));
        me = min(me, idpp<DPP_MIRR>(me));

        // sum butterfly (DPP-fusable adds)
        s += fdpp<DPP_XOR1>(s);
        s += fdpp<DPP_XOR2>(s);
        s += fdpp<DPP_HMIRR>(s);
        s += fdpp<DPP_MIRR>(s);

        const float inv = __builtin_amdgcn_rcpf(s);
        accp[0] = fmaf(e0, inv, accp[0]);
        accp[1] = fmaf(e1, inv, accp[1]);
        accp[2] = fmaf(e2, inv, accp[2]);
        accp[3] = fmaf(e3, inv, accp[3]);

        // z-loss: all 16 lanes of a token hold identical (m, s);
        // accumulate unconditionally, divide by 16 at the block fold
        const float lz = fmaf(__log2f(s), LN2, m);
        accz = fmaf(lz, lz, accz);

        if (c == 0)                        // lanes 0,16,32,48: one token each
            atomicAdd(&s_cnt[me], 1u);
    }

    // fold the 4 token-subgroups (lanes l, l^16, l^32 share an expert chunk)
#pragma unroll
    for (int j = 0; j < 4; ++j) {
        accp[j] += __shfl_xor(accp[j], 16);
        accp[j] += __shfl_xor(accp[j], 32);
    }
    if (lane < 16) {
#pragma unroll
        for (int j = 0; j < 4; ++j) atomicAdd(&s_ps[cb + j], accp[j]);
    }
    // z: every lane accumulated the token's lz^2 -> wave sum / 16
    accz += __shfl_xor(accz, 1);
    accz += __shfl_xor(accz, 2);
    accz += __shfl_xor(accz, 4);
    accz += __shfl_xor(accz, 8);
    accz += __shfl_xor(accz, 16);
    accz += __shfl_xor(accz, 32);
    if (lane == 0) atomicAdd(&s_z, accz * 0.0625f);
    __syncthreads();

    // per-block partials: plain stores, every slot owned by exactly one block
    const int row = blockIdx.x;
    if (tid < NE) {
        pps [row * NE + tid] = s_ps[tid];
        pcnt[row * NE + tid] = s_cnt[tid];
    }
    if (tid == 0) pz[row] = s_z;
}

__global__ __launch_bounds__(1024) void router_final(
    const float* __restrict__ pps,
    const unsigned int* __restrict__ pcnt,
    const float* __restrict__ pz,
    const int* __restrict__ capp,
    float* __restrict__ out)
{
    const int tid  = threadIdx.x;
    const int lane = tid & 63;   // expert
    const int w    = tid >> 6;   // wave 0..15
    const unsigned int C = (unsigned int)(*capp);

    __shared__ float s_aux[16];
    __shared__ float s_zz[16];

    float acc = 0.f;
#pragma unroll
    for (int gi = 0; gi < NG / 16; ++gi) {
        const int g = w + gi * 16;
        unsigned int n = 0u;
        float        P = 0.f;
#pragma unroll
        for (int b = 0; b < 32; ++b) {
            const int row = g * 32 + b;          // coalesced: lane = expert
            n += pcnt[row * NE + lane];
            P += pps [row * NE + lane];
        }
        float ovf = (n > C) ? (float)(n - C) : 0.f;
#pragma unroll
        for (int off = 1; off <= 32; off <<= 1) ovf += __shfl_xor(ovf, off);
        float ce = fminf((float)n, (float)C);
        if (lane == 0) ce += ovf;    // dropped tokens argmax to expert 0
        acc += ce * P;
    }
#pragma unroll
    for (int off = 1; off <= 32; off <<= 1) acc += __shfl_xor(acc, off);
    if (lane == 0) s_aux[w] = acc;

    // z: 2048 partials, two per thread
    float zz = pz[tid] + pz[tid + 1024];
#pragma unroll
    for (int off = 1; off <= 32; off <<= 1) zz += __shfl_xor(zz, off);
    if (lane == 0) s_zz[w] = zz;
    __syncthreads();

    if (tid == 0) {
        float A = 0.f, Z = 0.f;
#pragma unroll
        for (int i = 0; i < 16; ++i) { A += s_aux[i]; Z += s_zz[i]; }
        // aux = sum_e c_e * P_e * NE / (NG * NT * NT)
        const float aux_loss = A * ((float)NE / ((float)NG * (float)NT * (float)NT));
        const float z_loss   = Z / ((float)NG * (float)NT);
        out[0] = Z_COEF * z_loss + A_COEF * aux_loss;
    }
}

extern "C" void kernel_launch(void* const* d_in, const int* in_sizes, int n_in,
                              void* d_out, int out_size, void* d_ws, size_t ws_size,
                              hipStream_t stream)
{
    const float* logits = (const float*)d_in[0];
    // d_in[1] = attention_mask (unused by the reference forward)
    const int* cap = (const int*)d_in[2];

    float*        pps  = (float*)d_ws;
    unsigned int* pcnt = (unsigned int*)((char*)d_ws + (size_t)NBLK * NE * 4);
    float*        pz   = (float*)((char*)d_ws + 2ull * NBLK * NE * 4);

    router_main<<<NBLK, BLK, 0, stream>>>(logits, pps, pcnt, pz);
    router_final<<<1, 1024, 0, stream>>>(pps, pcnt, pz, cap, (float*)d_out);
}

// Round 10
// 35.181 us; speedup vs baseline: 1.2243x; 1.2243x over previous
//
#include <hip/hip_runtime.h>

#define NG 64
#define NT 8192
#define NE 64
#define Z_COEF 0.001f
#define A_COEF 0.001f

#define BLK 512                  // 8 waves
#define ITERS 4                  // 16 tokens per iter per wave
#define TPW 64                   // tokens per wave
#define TPB 512                  // tokens per block (8 waves * 64)
#define NBLK (NG * (NT / TPB))   // 1024 (16 blocks per group)

#define LOG2E 1.44269504088896340736f
#define LN2   0.69314718055994530942f
#define BIGIDX 1048576

#define DPP_XOR1  0xB1           // quad_perm(1,0,3,2)  : lane ^ 1
#define DPP_XOR2  0x4E           // quad_perm(2,3,0,1)  : lane ^ 2
#define DPP_HMIRR 0x141          // row_half_mirror     : lane ^ 7 within 8
#define DPP_MIRR  0x140          // row_mirror          : lane ^ 15 within 16

template <int CTRL>
__device__ __forceinline__ float fdpp(float x) {
    return __int_as_float(__builtin_amdgcn_mov_dpp(__float_as_int(x), CTRL, 0xF, 0xF, true));
}
template <int CTRL>
__device__ __forceinline__ int idpp(int x) {
    return __builtin_amdgcn_mov_dpp(x, CTRL, 0xF, 0xF, true);
}

// ws layout (all slots rewritten every launch, no memset node):
//   float pps [NBLK][NE]   per-block prob sums
//   uint  pcnt[NBLK][NE]   per-block argmax counts
//   float pz  [NBLK]       per-block z partials
//   float acc [2]          {aux-sum, z-sum}  (zeroed by main block 0)
//   uint  done             finalize counter  (zeroed by main block 0)

__global__ __launch_bounds__(BLK) void router_main(
    const float* __restrict__ logits,
    float* __restrict__ pps,
    unsigned int* __restrict__ pcnt,
    float* __restrict__ pz,
    float* __restrict__ accbuf,
    unsigned int* __restrict__ donep)
{
    const int tid  = threadIdx.x;
    const int lane = tid & 63;
    const int wv   = tid >> 6;       // wave in block 0..7
    const int c    = lane & 15;      // expert chunk: experts 4c .. 4c+3
    const int cb   = c << 2;

    // zero the finalize scalars for this launch (visible to router_final
    // via the kernel-boundary release; no extra graph node needed)
    if (blockIdx.x == 0 && tid == 0) {
        accbuf[0] = 0.f;
        accbuf[1] = 0.f;
        *donep    = 0u;
    }

    const int g     = blockIdx.x >> 4;                  // 16 blocks per group
    const int tbase = (blockIdx.x & 15) * TPB + wv * TPW;

    // fully coalesced: per instruction k, lane l reads bytes [k*1024 + l*16)
    // of the wave's 4KB token chunk -> token 4k+(l>>4), experts [4*(l&15),+4)
    const float* p0 = logits + ((size_t)g * NT + tbase) * NE + lane * 4;

    __shared__ float        s_ps[NE];
    __shared__ unsigned int s_cnt[NE];
    __shared__ float        s_z;
    if (tid < NE) { s_ps[tid] = 0.f; s_cnt[tid] = 0u; }
    if (tid == 0) s_z = 0.f;
    __syncthreads();

    float accp[4] = {0.f, 0.f, 0.f, 0.f};
    float accz = 0.f;

    for (int it = 0; it < ITERS; ++it) {
        const float* pi = p0 + (size_t)it * 1024;
        float4 cur[4];                       // 4 outstanding loads per wave
#pragma unroll
        for (int k = 0; k < 4; ++k)
            cur[k] = *reinterpret_cast<const float4*>(pi + k * 256);

#pragma unroll
        for (int k = 0; k < 4; ++k) {
            const float v0 = cur[k].x, v1 = cur[k].y, v2 = cur[k].z, v3 = cur[k].w;

            // group max: local max chain + 4 DPP-fusable fmax stages
            float m = fmaxf(fmaxf(v0, v1), fmaxf(v2, v3));
            m = fmaxf(m, fdpp<DPP_XOR1>(m));
            m = fmaxf(m, fdpp<DPP_XOR2>(m));
            m = fmaxf(m, fdpp<DPP_HMIRR>(m));
            m = fmaxf(m, fdpp<DPP_MIRR>(m));

            // exps straight against group max (base-2, single v_exp each)
            const float e0 = exp2f((v0 - m) * LOG2E);
            const float e1 = exp2f((v1 - m) * LOG2E);
            const float e2 = exp2f((v2 - m) * LOG2E);
            const float e3 = exp2f((v3 - m) * LOG2E);
            float s = (e0 + e1) + (e2 + e3);

            // argmax = first index whose value equals the max (exact ref ties)
            int me = BIGIDX;
            if (v3 == m) me = cb + 3;
            if (v2 == m) me = cb + 2;
            if (v1 == m) me = cb + 1;
            if (v0 == m) me = cb + 0;
            me = min(me, idpp<DPP_XOR1>(me));
            me = min(me, idpp<DPP_XOR2>(me));
            me = min(me, idpp<DPP_HMIRR>(me));
            me = min(me, idpp<DPP_MIRR>(me));

            // sum butterfly (DPP-fusable adds)
            s += fdpp<DPP_XOR1>(s);
            s += fdpp<DPP_XOR2>(s);
            s += fdpp<DPP_HMIRR>(s);
            s += fdpp<DPP_MIRR>(s);

            const float inv = __builtin_amdgcn_rcpf(s);
            accp[0] = fmaf(e0, inv, accp[0]);
            accp[1] = fmaf(e1, inv, accp[1]);
            accp[2] = fmaf(e2, inv, accp[2]);
            accp[3] = fmaf(e3, inv, accp[3]);

            // z-loss: all 16 lanes of a token hold identical (m, s);
            // accumulate unconditionally, divide by 16 at the block fold
            const float lz = fmaf(__log2f(s), LN2, m);
            accz = fmaf(lz, lz, accz);

            if (c == 0)                        // lanes 0,16,32,48: one token each
                atomicAdd(&s_cnt[me], 1u);
        }
    }

    // fold the 4 token-subgroups (lanes l, l^16, l^32 share an expert chunk)
#pragma unroll
    for (int j = 0; j < 4; ++j) {
        accp[j] += __shfl_xor(accp[j], 16);
        accp[j] += __shfl_xor(accp[j], 32);
    }
    if (lane < 16) {
#pragma unroll
        for (int j = 0; j < 4; ++j) atomicAdd(&s_ps[cb + j], accp[j]);
    }
    // z: every lane accumulated the token's lz^2 -> wave sum / 16
    accz += __shfl_xor(accz, 1);
    accz += __shfl_xor(accz, 2);
    accz += __shfl_xor(accz, 4);
    accz += __shfl_xor(accz, 8);
    accz += __shfl_xor(accz, 16);
    accz += __shfl_xor(accz, 32);
    if (lane == 0) atomicAdd(&s_z, accz * 0.0625f);
    __syncthreads();

    // per-block partials: plain stores, every slot owned by exactly one block
    const int row = blockIdx.x;
    if (tid < NE) {
        pps [row * NE + tid] = s_ps[tid];
        pcnt[row * NE + tid] = s_cnt[tid];
    }
    if (tid == 0) pz[row] = s_z;
}

// 64 blocks (one per group) x 1 wave: parallel partial-reduce + scalar
// atomics + done-counter epilogue (only 64 waves ever fence -> cheap).
__global__ __launch_bounds__(64) void router_final(
    const float* __restrict__ pps,
    const unsigned int* __restrict__ pcnt,
    const float* __restrict__ pz,
    const int* __restrict__ capp,
    float* __restrict__ accbuf,
    unsigned int* __restrict__ donep,
    float* __restrict__ out)
{
    const int lane = threadIdx.x;    // 0..63 = expert
    const int g    = blockIdx.x;     // group
    const unsigned int C = (unsigned int)(*capp);

    unsigned int n = 0u;
    float        P = 0.f;
#pragma unroll
    for (int b = 0; b < 16; ++b) {
        const int row = g * 16 + b;              // coalesced: lane = expert
        n += pcnt[row * NE + lane];
        P += pps [row * NE + lane];
    }

    float ovf = (n > C) ? (float)(n - C) : 0.f;
#pragma unroll
    for (int off = 1; off <= 32; off <<= 1) ovf += __shfl_xor(ovf, off);

    float ce = fminf((float)n, (float)C);
    if (lane == 0) ce += ovf;        // dropped tokens argmax to expert 0
    float term = ce * P;
#pragma unroll
    for (int off = 1; off <= 32; off <<= 1) term += __shfl_xor(term, off);

    float zz = (lane < 16) ? pz[g * 16 + lane] : 0.f;
#pragma unroll
    for (int off = 1; off <= 8; off <<= 1) zz += __shfl_xor(zz, off);

    if (lane == 0) {
        atomicAdd(&accbuf[0], term);
        atomicAdd(&accbuf[1], zz);
    }
    __threadfence();

    bool last = false;
    if (lane == 0)
        last = (atomicAdd(donep, 1u) == (unsigned int)(NG - 1));

    if (last) {                      // lane 0 of the last-arriving block
        const float A = __hip_atomic_load(&accbuf[0], __ATOMIC_RELAXED,
                                          __HIP_MEMORY_SCOPE_AGENT);
        const float Z = __hip_atomic_load(&accbuf[1], __ATOMIC_RELAXED,
                                          __HIP_MEMORY_SCOPE_AGENT);
        const float aux_loss = A * ((float)NE / ((float)NG * (float)NT * (float)NT));
        const float z_loss   = Z / ((float)NG * (float)NT);
        out[0] = Z_COEF * z_loss + A_COEF * aux_loss;
    }
}

extern "C" void kernel_launch(void* const* d_in, const int* in_sizes, int n_in,
                              void* d_out, int out_size, void* d_ws, size_t ws_size,
                              hipStream_t stream)
{
    const float* logits = (const float*)d_in[0];
    // d_in[1] = attention_mask (unused by the reference forward)
    const int* cap = (const int*)d_in[2];

    float*        pps    = (float*)d_ws;
    unsigned int* pcnt   = (unsigned int*)((char*)d_ws + (size_t)NBLK * NE * 4);
    float*        pz     = (float*)((char*)d_ws + 2ull * NBLK * NE * 4);
    float*        accbuf = (float*)((char*)d_ws + 2ull * NBLK * NE * 4 + NBLK * 4);
    unsigned int* donep  = (unsigned int*)((char*)d_ws + 2ull * NBLK * NE * 4 + NBLK * 4 + 8);

    router_main<<<NBLK, BLK, 0, stream>>>(logits, pps, pcnt, pz, accbuf, donep);
    router_final<<<NG, 64, 0, stream>>>(pps, pcnt, pz, cap, accbuf, donep,
                                        (float*)d_out);
}